// Round 4
// baseline (28.787 us; speedup 1.0000x reference)
//
#include <hip/hip_runtime.h>

// Advection: out[b,i,j] = (s[b,min(i+1,H-1),j]-s[b,i,j])*v[b,i,j,0]
//                       + (s[b,i,min(j+1,W-1)]-s[b,i,j])*v[b,i,j,1]
// B=32, H=W=512, fp32. Memory-bound elementwise stencil.
// 4 px/thread contiguous (16B/lane, perfect coalescing).
// Vertical strip blocking: each block does 4 chunks (8 rows) of one image,
// so the dy row-overlap is 1/8 instead of 1/2 and intra-block re-reads hit L1.
// XCD-bijective swizzle keeps adjacent strips on the same XCD's L2.

#define H 512
#define W 512
#define PLANE (H * W)            // 262144
#define CHUNK_PX 1024            // 256 threads * 4 px = 2 rows
#define CHUNKS_PER_BLOCK 4       // 8 rows per block

typedef float f4 __attribute__((ext_vector_type(4)));

__global__ __launch_bounds__(256) void advect_kernel(
    const float* __restrict__ s,
    const float* __restrict__ v,
    float* __restrict__ out)
{
    // 2048 blocks; hw block n -> XCD n%8. Map so logically-adjacent strips
    // share an XCD: logical = (n%8)*256 + n/8  (bijective, 2048 = 8*256).
    const int logical = (blockIdx.x & 7) * 256 + (blockIdx.x >> 3);
    const int chunk0 = logical * CHUNKS_PER_BLOCK;

    #pragma unroll
    for (int c = 0; c < CHUNKS_PER_BLOCK; ++c) {
        const int q = (chunk0 + c) * CHUNK_PX + (threadIdx.x << 2);
        const int b   = q >> 18;              // / PLANE
        const int rem = q & (PLANE - 1);
        const int i   = rem >> 9;             // / W
        const int j   = rem & (W - 1);

        const float* srow   = s + (size_t)b * PLANE + (size_t)i * W;
        const int    idn    = (i + 1 < H) ? (i + 1) : (H - 1);
        const float* srowdn = s + (size_t)b * PLANE + (size_t)idn * W;

        const f4 s0 = *reinterpret_cast<const f4*>(srow + j);
        const f4 sd = *reinterpret_cast<const f4*>(srowdn + j);
        // right neighbor of px j+3 is j+4, clamped to W-1 (== s0.w at edge)
        const float s4 = (j + 4 < W) ? srow[j + 4] : s0.w;

        const f4 v01 = *reinterpret_cast<const f4*>(v + (size_t)q * 2);
        const f4 v23 = *reinterpret_cast<const f4*>(v + (size_t)q * 2 + 4);

        f4 o;
        o.x = (sd.x - s0.x) * v01.x + (s0.y - s0.x) * v01.y;
        o.y = (sd.y - s0.y) * v01.z + (s0.z - s0.y) * v01.w;
        o.z = (sd.z - s0.z) * v23.x + (s0.w - s0.z) * v23.y;
        o.w = (sd.w - s0.w) * v23.z + (s4   - s0.w) * v23.w;

        *reinterpret_cast<f4*>(out + q) = o;
    }
}

extern "C" void kernel_launch(void* const* d_in, const int* in_sizes, int n_in,
                              void* d_out, int out_size, void* d_ws, size_t ws_size,
                              hipStream_t stream) {
    const float* s = (const float*)d_in[0];   // [32,512,512,1] f32
    const float* v = (const float*)d_in[1];   // [32,512,512,2] f32
    float* out = (float*)d_out;               // [32,512,512,1] f32

    const int n_pixels = 32 * PLANE;                          // 8,388,608
    const int grid = n_pixels / (CHUNK_PX * CHUNKS_PER_BLOCK); // 2048
    advect_kernel<<<grid, 256, 0, stream>>>(s, v, out);
}

// Round 5
// 26.978 us; speedup vs baseline: 1.0671x; 1.0671x over previous
//
#include <hip/hip_runtime.h>

// Advection: out[b,i,j] = (s[b,min(i+1,H-1),j]-s[b,i,j])*v[b,i,j,0]
//                       + (s[b,i,min(j+1,W-1)]-s[b,i,j])*v[b,i,j,1]
// B=32, H=W=512, fp32. Latency-bound (rocprof R4: all pipes <60%, inputs
// L3-resident). Strategy: 2 independent fully-coalesced pixel quads per
// thread (4M px apart) -> ~11 VMEM loads in flight per thread, per-
// instruction coalescing identical to R1 (16B/lane contiguous).

#define H 512
#define W 512
#define PLANE (H * W)          // 262144
#define HALF_PX (1 << 22)      // 4,194,304 = half of 8,388,608

typedef float f4 __attribute__((ext_vector_type(4)));

__global__ __launch_bounds__(256) void advect_kernel(
    const float* __restrict__ s,
    const float* __restrict__ v,
    float* __restrict__ out)
{
    const int t  = blockIdx.x * blockDim.x + threadIdx.x;
    const int q0 = t << 2;             // quad in first half
    const int q1 = q0 + HALF_PX;       // quad in second half

    // ---- addresses for stream 0 ----
    const int b0   = q0 >> 18;
    const int rem0 = q0 & (PLANE - 1);
    const int i0   = rem0 >> 9;
    const int j0   = rem0 & (W - 1);
    const float* srow0   = s + (size_t)b0 * PLANE + (size_t)i0 * W;
    const float* srowdn0 = srow0 + ((i0 + 1 < H) ? W : 0);

    // ---- addresses for stream 1 ----
    const int b1   = q1 >> 18;
    const int rem1 = q1 & (PLANE - 1);
    const int i1   = rem1 >> 9;
    const int j1   = rem1 & (W - 1);
    const float* srow1   = s + (size_t)b1 * PLANE + (size_t)i1 * W;
    const float* srowdn1 = srow1 + ((i1 + 1 < H) ? W : 0);

    // ---- issue ALL loads before any use (MLP) ----
    const f4 s0a = *reinterpret_cast<const f4*>(srow0 + j0);
    const f4 sda = *reinterpret_cast<const f4*>(srowdn0 + j0);
    const f4 s0b = *reinterpret_cast<const f4*>(srow1 + j1);
    const f4 sdb = *reinterpret_cast<const f4*>(srowdn1 + j1);
    const float s4a = (j0 + 4 < W) ? srow0[j0 + 4] : srow0[W - 1];
    const float s4b = (j1 + 4 < W) ? srow1[j1 + 4] : srow1[W - 1];
    const f4 va0 = *reinterpret_cast<const f4*>(v + (size_t)q0 * 2);
    const f4 va1 = *reinterpret_cast<const f4*>(v + (size_t)q0 * 2 + 4);
    const f4 vb0 = *reinterpret_cast<const f4*>(v + (size_t)q1 * 2);
    const f4 vb1 = *reinterpret_cast<const f4*>(v + (size_t)q1 * 2 + 4);

    f4 o0, o1;
    o0.x = (sda.x - s0a.x) * va0.x + (s0a.y - s0a.x) * va0.y;
    o0.y = (sda.y - s0a.y) * va0.z + (s0a.z - s0a.y) * va0.w;
    o0.z = (sda.z - s0a.z) * va1.x + (s0a.w - s0a.z) * va1.y;
    o0.w = (sda.w - s0a.w) * va1.z + (s4a   - s0a.w) * va1.w;

    o1.x = (sdb.x - s0b.x) * vb0.x + (s0b.y - s0b.x) * vb0.y;
    o1.y = (sdb.y - s0b.y) * vb0.z + (s0b.z - s0b.y) * vb0.w;
    o1.z = (sdb.z - s0b.z) * vb1.x + (s0b.w - s0b.z) * vb1.y;
    o1.w = (sdb.w - s0b.w) * vb1.z + (s4b   - s0b.w) * vb1.w;

    *reinterpret_cast<f4*>(out + q0) = o0;
    *reinterpret_cast<f4*>(out + q1) = o1;
}

extern "C" void kernel_launch(void* const* d_in, const int* in_sizes, int n_in,
                              void* d_out, int out_size, void* d_ws, size_t ws_size,
                              hipStream_t stream) {
    const float* s = (const float*)d_in[0];   // [32,512,512,1] f32
    const float* v = (const float*)d_in[1];   // [32,512,512,2] f32
    float* out = (float*)d_out;               // [32,512,512,1] f32

    const int threads = HALF_PX / 4;          // 1,048,576
    const int block = 256;
    const int grid = threads / block;         // 4096
    advect_kernel<<<grid, block, 0, stream>>>(s, v, out);
}

// Round 6
// 25.048 us; speedup vs baseline: 1.1493x; 1.0770x over previous
//
#include <hip/hip_runtime.h>

// Advection: out[b,i,j] = (s[b,min(i+1,H-1),j]-s[b,i,j])*v[b,i,j,0]
//                       + (s[b,i,min(j+1,W-1)]-s[b,i,j])*v[b,i,j,1]
// B=32, H=W=512, fp32. Latency/concurrency-bound (R4 rocprof: all pipes
// idle, occupancy ~55% with no static limiter). R1 structure unchanged;
// block 256 -> 1024 so full wave occupancy needs only 2 resident WGs/CU.

#define H 512
#define W 512
#define PLANE (H * W)   // 262144

typedef float f4 __attribute__((ext_vector_type(4)));

__global__ __launch_bounds__(1024) void advect_kernel(
    const float* __restrict__ s,
    const float* __restrict__ v,
    float* __restrict__ out)
{
    const int t = blockIdx.x * blockDim.x + threadIdx.x;
    const int q = t << 2;                 // flat pixel index (4 pixels/thread)
    const int b   = q >> 18;              // / PLANE
    const int rem = q & (PLANE - 1);
    const int i   = rem >> 9;             // / W
    const int j   = rem & (W - 1);

    const float* srow   = s + (size_t)b * PLANE + (size_t)i * W;
    const int    idn    = (i + 1 < H) ? (i + 1) : (H - 1);
    const float* srowdn = s + (size_t)b * PLANE + (size_t)idn * W;

    const f4 s0 = *reinterpret_cast<const f4*>(srow + j);
    const f4 sd = *reinterpret_cast<const f4*>(srowdn + j);
    // right neighbor of pixel j+3 is j+4, clamped to W-1 (== s0.w at row edge)
    const float s4 = (j + 4 < W) ? srow[j + 4] : s0.w;

    const f4 v01 = *reinterpret_cast<const f4*>(v + (size_t)q * 2);
    const f4 v23 = *reinterpret_cast<const f4*>(v + (size_t)q * 2 + 4);

    f4 o;
    o.x = (sd.x - s0.x) * v01.x + (s0.y - s0.x) * v01.y;
    o.y = (sd.y - s0.y) * v01.z + (s0.z - s0.y) * v01.w;
    o.z = (sd.z - s0.z) * v23.x + (s0.w - s0.z) * v23.y;
    o.w = (sd.w - s0.w) * v23.z + (s4   - s0.w) * v23.w;

    *reinterpret_cast<f4*>(out + q) = o;
}

extern "C" void kernel_launch(void* const* d_in, const int* in_sizes, int n_in,
                              void* d_out, int out_size, void* d_ws, size_t ws_size,
                              hipStream_t stream) {
    const float* s = (const float*)d_in[0];   // [32,512,512,1] f32
    const float* v = (const float*)d_in[1];   // [32,512,512,2] f32
    float* out = (float*)d_out;               // [32,512,512,1] f32

    const int n_pixels = 32 * PLANE;          // 8,388,608
    const int threads = n_pixels / 4;         // 2,097,152
    const int block = 1024;
    const int grid = threads / block;         // 2048
    advect_kernel<<<grid, block, 0, stream>>>(s, v, out);
}

// Round 7
// 24.752 us; speedup vs baseline: 1.1630x; 1.0120x over previous
//
#include <hip/hip_runtime.h>

// Advection: out[b,i,j] = (s[b,min(i+1,H-1),j]-s[b,i,j])*v[b,i,j,0]
//                       + (s[b,i,min(j+1,W-1)]-s[b,i,j])*v[b,i,j,1]
// B=32, H=W=512, fp32.
// Layout: every VMEM instruction 100% lane-contiguous. Each wave owns 256
// consecutive px (2 chunks of 128). Thread (lane l) owns px pair (2l,2l+1)
// in each chunk -> velocity float4 @16B/lane, state float2 @8B/lane,
// store float2 @8B/lane, all perfectly packed per instruction.

#define H 512
#define W 512
#define PLANE (H * W)   // 262144

typedef float f2 __attribute__((ext_vector_type(2)));
typedef float f4 __attribute__((ext_vector_type(4)));

__global__ __launch_bounds__(1024) void advect_kernel(
    const float* __restrict__ s,
    const float* __restrict__ v,
    float* __restrict__ out)
{
    const int lane = threadIdx.x & 63;
    const int gw   = blockIdx.x * (1024 / 64) + (threadIdx.x >> 6); // global wave
    const int base = gw << 8;                                      // 256 px/wave

    // ---- chunk A: px = base + 2*lane ----
    const int pA   = base + (lane << 1);
    const int bA   = pA >> 18;
    const int remA = pA & (PLANE - 1);
    const int iA   = remA >> 9;
    const int jA   = remA & (W - 1);
    const float* srowA   = s + (size_t)bA * PLANE + (size_t)iA * W;
    const float* srowdnA = srowA + ((iA + 1 < H) ? W : 0);

    // ---- chunk B: px = base + 128 + 2*lane ----
    const int pB   = pA + 128;
    const int bB   = pB >> 18;
    const int remB = pB & (PLANE - 1);
    const int iB   = remB >> 9;
    const int jB   = remB & (W - 1);
    const float* srowB   = s + (size_t)bB * PLANE + (size_t)iB * W;
    const float* srowdnB = srowB + ((iB + 1 < H) ? W : 0);

    // ---- issue all loads before any use ----
    const f2 s0A = *reinterpret_cast<const f2*>(srowA + jA);
    const f2 sdA = *reinterpret_cast<const f2*>(srowdnA + jA);
    const f2 s0B = *reinterpret_cast<const f2*>(srowB + jB);
    const f2 sdB = *reinterpret_cast<const f2*>(srowdnB + jB);
    // right neighbor of px jA+1 is jA+2, clamped to W-1 (j is even, <= 510)
    const float s2A = srowA[(jA + 2 < W) ? jA + 2 : W - 1];
    const float s2B = srowB[(jB + 2 < W) ? jB + 2 : W - 1];
    const f4 vA = *reinterpret_cast<const f4*>(v + (size_t)pA * 2);
    const f4 vB = *reinterpret_cast<const f4*>(v + (size_t)pB * 2);

    f2 oA, oB;
    oA.x = (sdA.x - s0A.x) * vA.x + (s0A.y - s0A.x) * vA.y;
    oA.y = (sdA.y - s0A.y) * vA.z + (s2A   - s0A.y) * vA.w;
    oB.x = (sdB.x - s0B.x) * vB.x + (s0B.y - s0B.x) * vB.y;
    oB.y = (sdB.y - s0B.y) * vB.z + (s2B   - s0B.y) * vB.w;

    *reinterpret_cast<f2*>(out + pA) = oA;
    *reinterpret_cast<f2*>(out + pB) = oB;
}

extern "C" void kernel_launch(void* const* d_in, const int* in_sizes, int n_in,
                              void* d_out, int out_size, void* d_ws, size_t ws_size,
                              hipStream_t stream) {
    const float* s = (const float*)d_in[0];   // [32,512,512,1] f32
    const float* v = (const float*)d_in[1];   // [32,512,512,2] f32
    float* out = (float*)d_out;               // [32,512,512,1] f32

    const int n_pixels = 32 * PLANE;          // 8,388,608
    const int block = 1024;
    const int px_per_block = 4 * block;       // 4096 (4 px/thread)
    const int grid = n_pixels / px_per_block; // 2048
    advect_kernel<<<grid, block, 0, stream>>>(s, v, out);
}